// Round 7
// baseline (174.719 us; speedup 1.0000x reference)
//
#include <hip/hip_runtime.h>
#include <cstddef>

// B=16, h=8, Ch=32, H=W=56, N=3136
//   heads 0-1 -> 3x3 (w3,b3), cbase hh*32
//   heads 2-4 -> 5x5 (w5,b5), cbase hh*32-64
//   heads 5-7 -> 7x7 (w7,b7), cbase hh*32-160
// out[b][n][hh*32+ch] = q[b][hh][n][ch] * dwconv(v)[b][hh][n][ch]
//
// R12: L2-resident scheduling. R5-R11 (6 structures: occupancy 4-16
// waves/CU, issue volume 2.5x, write co-residency, intra-block overlap)
// are ALL pinned at ~53us with compulsory HBM bytes => per-CU memory
// service rate capped ~13 GB/s: queue-depth/latency-bound. Little's law
// says the only lever left is LATENCY PER REQUEST. This round makes each
// XCD round's working set fit its 4MB L2: slab 14->7 rows, grid 1024,
// each XCD round = 4 (b,head) planes x 8 y-slabs (v+q = 3.2MB <= 4MB L2)
// -> staging + halo reads become L2 hits (~200cy vs 600-900cy).
// Rounds balanced by tap cost via plane permutation (132/132/108/108).
// Compute structure = R9 (multi-row-per-lane, lowest issue volume).

#define BH 16
#define NH 8
#define CH 32
#define HW 56
#define NN (HW*HW)
#define ROWB (HW*CH*4)          // 7168 B per image row
#define RS 58                   // LDS row stride in px (56 + 2 gap)
#define NROWS_MAX 13            // 7 + 2*3 (K=7)
#define BUF_PX (3 + NROWS_MAX*RS + 1)   // 758 px
#define BUF_FLOATS (BUF_PX*CH)  // 24256 floats = 97024 B

typedef float f32x4 __attribute__((ext_vector_type(4)));
typedef unsigned int u32x4 __attribute__((ext_vector_type(4)));

__device__ __forceinline__ f32x4 bload(__amdgpu_buffer_rsrc_t rs, int voff) {
    u32x4 u = __builtin_amdgcn_raw_buffer_load_b128(rs, voff, 0, 0);
    f32x4 f; __builtin_memcpy(&f, &u, 16); return f;
}

// One wave computes R consecutive output rows (y0+sw .. y0+sw+R-1).
// Staged rows s = sw+rr, rr in [0, R+2P): window read ONCE, applied to
// every output row u with dy = rr - u in [0,K). (Proven R9.)
template<int K, int R>
__device__ __forceinline__ void conv_rows(
    const float* __restrict__ q, float* __restrict__ out,
    const float* __restrict__ bias,
    int b, int hh, int y0, int sw, int cbase,
    const float* __restrict__ w_lds, const float* __restrict__ bufs,
    int lane)
{
    constexpr int P  = K / 2;
    constexpr int NR = 7 + K - 1;       // window px per 7-px strip
    const int xseg = lane >> 3;         // 8 x-strips of 7 px
    const int chq  = lane & 7;          // 8 ch-quads
    const int x0   = xseg * 7;
    const int ch   = chq * 4;

    // K=7 edge masks: window px -3/+58 land on neighbor-row data (not gap).
    const float mL = (xseg == 0) ? 0.f : 1.f;
    const float mR = (xseg == 7) ? 0.f : 1.f;

    const f32x4 bias4 = *(const f32x4*)(bias + cbase + ch);
    f32x4 acc[R][7];
#pragma unroll
    for (int u = 0; u < R; ++u)
#pragma unroll
        for (int i = 0; i < 7; ++i) acc[u][i] = bias4;

    // rr loop RUNTIME (bounds icache); guards are wave-uniform.
    for (int rr = 0; rr < R + 2 * P; ++rr) {
        const float* rb = bufs + (size_t)((3 - P + x0) + (sw + rr) * RS) * CH + ch;
        f32x4 r[NR];
#pragma unroll
        for (int j = 0; j < NR; ++j)
            r[j] = *(const f32x4*)(rb + j * CH);
        if constexpr (K == 7) { r[0] *= mL; r[NR - 1] *= mR; }

#pragma unroll
        for (int u = 0; u < R; ++u) {
            const int dy = rr - u;
            if ((unsigned)dy < (unsigned)K) {
#pragma unroll
                for (int dx = 0; dx < K; ++dx) {
                    const f32x4 w4 = *(const f32x4*)(w_lds + (dy * K + dx) * CH + ch);
#pragma unroll
                    for (int i = 0; i < 7; ++i)
                        acc[u][i] += r[i + dx] * w4;
                }
            }
        }
    }

    // Epilogue per row: q load, multiply, plain store (full 128-B lines).
    const size_t plane = ((size_t)b * NH + hh) * (size_t)NN * CH;
#pragma unroll
    for (int u = 0; u < R; ++u) {
        const int y = y0 + sw + u;
        const float* qrow = q + plane + (size_t)y * (HW * CH);
        float* obase = out + ((size_t)b * NN + (size_t)y * HW) * (NH * CH) + hh * CH + ch;
#pragma unroll
        for (int i = 0; i < 7; ++i) {
            const int px = x0 + i;
            const f32x4 q4 = *(const f32x4*)(qrow + (size_t)px * CH + ch);
            *(f32x4*)(obase + (size_t)px * (NH * CH)) = acc[u][i] * q4;
        }
    }
}

template<int K>
__device__ __forceinline__ void run_head(
    const float* __restrict__ q, const float* __restrict__ v,
    const float* __restrict__ w, const float* __restrict__ bias,
    float* __restrict__ out, int b, int hh, int y0, int cbase,
    float* __restrict__ w_lds, float* __restrict__ bufs)
{
    constexpr int P = K / 2;
    constexpr int NROWS = 7 + 2 * P;    // staged rows per block
    const int t = threadIdx.x;

    // Stage weights into LDS, layout [tap][c].
    const int nw = K * K * CH;
    for (int i = t; i < nw; i += 256) {
        int tap = i >> 5, c = i & 31;
        w_lds[tap * CH + c] = w[(cbase + c) * (K * K) + tap];
    }

    // Zero pad px: lead 3, 2-px gap after each row, 1 trailing.
    {
        f32x4 z = {0.f, 0.f, 0.f, 0.f};
        const int NG = 3 + 2 * NROWS + 1;
        for (int i = t; i < NG * 8; i += 256) {
            const int g = i >> 3, sub = i & 7;
            int px;
            if (g < 3) px = g;
            else if (g < 3 + 2 * NROWS) {
                const int s = (g - 3) >> 1;
                px = 3 + s * RS + 56 + ((g - 3) & 1);
            } else px = 3 + NROWS * RS;
            *(f32x4*)(bufs + (size_t)px * CH + sub * 4) = z;
        }
    }

    const int wid  = t >> 6;
    const int lane = t & 63;
    const size_t plane = ((size_t)b * NH + hh) * (size_t)NN * CH;
    const float* vb = v + plane;

    // Cooperative staging: wave wid stages rows wid, wid+4, wid+8, wid+12.
    // Loads all issued first, then LDS writes (max VMEM overlap).
    // OOB rows: num_records=0 -> zeros = y zero-padding (proven R2-R4).
    f32x4 ld[4][7];
#pragma unroll
    for (int n = 0; n < 4; ++n) {
        const int s = wid + n * 4;
        if (s < NROWS) {
            const int gy = y0 - P + s;
            const bool ok = (unsigned)gy < (unsigned)HW;
            __amdgpu_buffer_rsrc_t rs = __builtin_amdgcn_make_buffer_rsrc(
                (void*)(vb + (ptrdiff_t)gy * (HW * CH)), (short)0, ok ? ROWB : 0, 0x00020000);
#pragma unroll
            for (int k = 0; k < 7; ++k) ld[n][k] = bload(rs, k * 1024 + lane * 16);
        }
    }
#pragma unroll
    for (int n = 0; n < 4; ++n) {
        const int s = wid + n * 4;
        if (s < NROWS) {
            float* dst = bufs + (size_t)(3 + s * RS) * CH;
#pragma unroll
            for (int k = 0; k < 7; ++k)
                *(f32x4*)(dst + k * 256 + lane * 4) = ld[n][k];
        }
    }
    __syncthreads();                    // only barrier in the kernel

    // 7 output rows split {2,2,2,1} over 4 waves.
    if      (wid == 0) conv_rows<K, 2>(q, out, bias, b, hh, y0, 0, cbase, w_lds, bufs, lane);
    else if (wid == 1) conv_rows<K, 2>(q, out, bias, b, hh, y0, 2, cbase, w_lds, bufs, lane);
    else if (wid == 2) conv_rows<K, 2>(q, out, bias, b, hh, y0, 4, cbase, w_lds, bufs, lane);
    else               conv_rows<K, 1>(q, out, bias, b, hh, y0, 6, cbase, w_lds, bufs, lane);
}

__global__ __launch_bounds__(256, 1)   // 103.3 KB LDS -> 1 block/CU
void clusterformer_fused(const float* __restrict__ q, const float* __restrict__ v,
                         const float* __restrict__ w3, const float* __restrict__ b3,
                         const float* __restrict__ w5, const float* __restrict__ b5,
                         const float* __restrict__ w7, const float* __restrict__ b7,
                         float* __restrict__ out)
{
    __shared__ __align__(16) float bufs[BUF_FLOATS];   // 97024 B
    __shared__ __align__(16) float w_lds[49 * CH];     // 6272 B

    // bid -> (xcd, round, plane-in-round, y-slab). Each XCD round
    // (32 blocks = 32 CUs) covers 4 (b,head) planes x 8 slabs:
    // v+q working set 3.2MB <= 4MB L2 -> staging/halo reads are L2 hits.
    // Plane permutation balances tap cost per round: {132,132,108,108}.
    const int bid  = blockIdx.x;       // 0..1023
    const int xcd  = bid & 7;
    const int slot = bid >> 3;         // 0..127 within XCD
    const int rnd  = slot >> 5;        // 0..3 (temporal round)
    const int ps   = (slot >> 3) & 3;  // plane within round
    const int yg   = slot & 7;         // y-slab
    const int pp   = rnd * 4 + ps;     // 0..15
    // pp -> (hh, b_hi): each pair exactly once; heavy rounds first.
    const int hh   = (int)((0x1437042613570265ULL >> (pp * 4)) & 0xF);
    const int b_hi = (0xFB20 >> pp) & 1;
    const int b    = (b_hi << 3) | xcd;
    const int y0   = yg * 7;

    if (hh < 2)      run_head<3>(q, v, w3, b3, out, b, hh, y0, hh * 32,       w_lds, bufs);
    else if (hh < 5) run_head<5>(q, v, w5, b5, out, b, hh, y0, hh * 32 - 64,  w_lds, bufs);
    else             run_head<7>(q, v, w7, b7, out, b, hh, y0, hh * 32 - 160, w_lds, bufs);
}

extern "C" void kernel_launch(void* const* d_in, const int* in_sizes, int n_in,
                              void* d_out, int out_size, void* d_ws, size_t ws_size,
                              hipStream_t stream) {
    const float* q  = (const float*)d_in[0];
    const float* v  = (const float*)d_in[1];
    const float* w3 = (const float*)d_in[2];
    const float* b3 = (const float*)d_in[3];
    const float* w5 = (const float*)d_in[4];
    const float* b5 = (const float*)d_in[5];
    const float* w7 = (const float*)d_in[6];
    const float* b7 = (const float*)d_in[7];
    float* out = (float*)d_out;

    const int grid = BH * NH * 8;      // 1024 blocks of 256 threads
    clusterformer_fused<<<grid, 256, 0, stream>>>(q, v, w3, b3, w5, b5, w7, b7, out);
}